// Round 1
// baseline (306.863 us; speedup 1.0000x reference)
//
#include <hip/hip_runtime.h>

#define T_SEQ 512
#define NH 8
#define DEPTH 64
#define UNITS_ 512
#define SCALE2 2.8853900817779268f   // 2*log2(e)
#define LOG2E 1.4426950408889634f

// ================= GEMM with bias: C = A@W + bias =================
// A:[M,K], W:[K,N], C:[M,N], all row-major fp32. Tile 32(M)x64(N), K-step 32.
// blockIdx.z selects the (A,W,bias,C) pointer set (Q-proj vs K-proj batching).
__global__ __launch_bounds__(256) void gemm_bias(
    const float* __restrict__ A0, const float* __restrict__ A1,
    const float* __restrict__ W0, const float* __restrict__ W1,
    const float* __restrict__ bias0, const float* __restrict__ bias1,
    float* __restrict__ C0, float* __restrict__ C1,
    int M, int N, int K)
{
    const float* A = blockIdx.z ? A1 : A0;
    const float* W = blockIdx.z ? W1 : W0;
    const float* bias = blockIdx.z ? bias1 : bias0;
    float* C = blockIdx.z ? C1 : C0;

    __shared__ float As[32][36];   // transposed: As[k][m], pad->bank rotate
    __shared__ float Bs[32][68];   // Bs[k][n]

    const int tid = threadIdx.x;
    const int m0 = blockIdx.y * 32;
    const int n0 = blockIdx.x * 64;
    const int ti = tid >> 4;       // 0..15 -> rows 2ti, 2ti+1
    const int tj = tid & 15;       // cols 4tj..4tj+3

    const int arow = tid >> 3;         // 0..31
    const int akc = (tid & 7) * 4;     // 0..28
    const int bkr = tid >> 4;          // 0..15 (and +16)
    const int bnc = (tid & 15) * 4;

    float4 acc0 = make_float4(0.f, 0.f, 0.f, 0.f);
    float4 acc1 = make_float4(0.f, 0.f, 0.f, 0.f);

    for (int k0 = 0; k0 < K; k0 += 32) {
        float4 av = *(const float4*)&A[(m0 + arow) * K + k0 + akc];
        float4 bv0 = *(const float4*)&W[(k0 + bkr) * N + n0 + bnc];
        float4 bv1 = *(const float4*)&W[(k0 + bkr + 16) * N + n0 + bnc];
        __syncthreads();
        As[akc + 0][arow] = av.x;
        As[akc + 1][arow] = av.y;
        As[akc + 2][arow] = av.z;
        As[akc + 3][arow] = av.w;
        *(float4*)&Bs[bkr][bnc] = bv0;
        *(float4*)&Bs[bkr + 16][bnc] = bv1;
        __syncthreads();
        #pragma unroll
        for (int kk = 0; kk < 32; ++kk) {
            float2 a2 = *(const float2*)&As[kk][2 * ti];
            float4 b4 = *(const float4*)&Bs[kk][4 * tj];
            acc0.x = fmaf(a2.x, b4.x, acc0.x);
            acc0.y = fmaf(a2.x, b4.y, acc0.y);
            acc0.z = fmaf(a2.x, b4.z, acc0.z);
            acc0.w = fmaf(a2.x, b4.w, acc0.w);
            acc1.x = fmaf(a2.y, b4.x, acc1.x);
            acc1.y = fmaf(a2.y, b4.y, acc1.y);
            acc1.z = fmaf(a2.y, b4.z, acc1.z);
            acc1.w = fmaf(a2.y, b4.w, acc1.w);
        }
    }
    const int m = m0 + 2 * ti;
    const int n = n0 + 4 * tj;
    float4 bb = *(const float4*)&bias[n];
    float4 o0 = make_float4(acc0.x + bb.x, acc0.y + bb.y, acc0.z + bb.z, acc0.w + bb.w);
    float4 o1 = make_float4(acc1.x + bb.x, acc1.y + bb.y, acc1.z + bb.z, acc1.w + bb.w);
    *(float4*)&C[m * N + n] = o0;
    *(float4*)&C[(m + 1) * N + n] = o1;
}

// ============ per-head transform: qq2/kkb2 (+Kh copy) ============
// which=0: qq2[b,h,t,e] = SCALE2 * sum_d Q[b,t,h*64+d] * Wq_h[h,d,e]
// which=1: kkb2[b,h,s,e] = SCALE2 * (sum_d K[..]*Wk_h[h,d,e] + b_h[h,e]);
//          also Kh[b,h,s,d] = K[b,s,h*64+d]
__global__ __launch_bounds__(256) void head_xform(
    const float* __restrict__ In0, const float* __restrict__ In1,
    const float* __restrict__ Wh0, const float* __restrict__ Wh1,
    const float* __restrict__ bh,
    float* __restrict__ qq2, float* __restrict__ kkb2,
    float* __restrict__ Kh)
{
    __shared__ float As[64][68];   // As[d][t] (transposed input tile)
    __shared__ float Ws[64][68];   // Ws[d][e]

    const int tid = threadIdx.x;
    const int t0 = blockIdx.x * 64;
    const int h = blockIdx.y;
    const int which = blockIdx.z & 1;
    const int b = blockIdx.z >> 1;

    const float* In = which ? In1 : In0;
    const float* Wp = (which ? Wh1 : Wh0) + h * DEPTH * DEPTH;
    float* outp = (which ? kkb2 : qq2) + ((b * NH + h) * T_SEQ + t0) * DEPTH;
    float* Khp = Kh + ((b * NH + h) * T_SEQ + t0) * DEPTH;

    const int e4 = (tid & 15) * 4;
    const int tr = tid >> 4;

    #pragma unroll
    for (int r = 0; r < 4; ++r) {
        const int t = tr + 16 * r;
        float4 v = *(const float4*)&In[(b * T_SEQ + t0 + t) * UNITS_ + h * DEPTH + e4];
        As[e4 + 0][t] = v.x;
        As[e4 + 1][t] = v.y;
        As[e4 + 2][t] = v.z;
        As[e4 + 3][t] = v.w;
        if (which) *(float4*)&Khp[t * DEPTH + e4] = v;
        *(float4*)&Ws[t][e4] = *(const float4*)&Wp[t * DEPTH + e4];  // t plays role of d
    }
    __syncthreads();

    const int ti = tid >> 4;
    const int tj = tid & 15;
    float4 acc[4];
    acc[0] = acc[1] = acc[2] = acc[3] = make_float4(0.f, 0.f, 0.f, 0.f);
    #pragma unroll 8
    for (int d = 0; d < 64; ++d) {
        float4 a4 = *(const float4*)&As[d][4 * ti];
        float4 b4 = *(const float4*)&Ws[d][4 * tj];
        acc[0].x = fmaf(a4.x, b4.x, acc[0].x);
        acc[0].y = fmaf(a4.x, b4.y, acc[0].y);
        acc[0].z = fmaf(a4.x, b4.z, acc[0].z);
        acc[0].w = fmaf(a4.x, b4.w, acc[0].w);
        acc[1].x = fmaf(a4.y, b4.x, acc[1].x);
        acc[1].y = fmaf(a4.y, b4.y, acc[1].y);
        acc[1].z = fmaf(a4.y, b4.z, acc[1].z);
        acc[1].w = fmaf(a4.y, b4.w, acc[1].w);
        acc[2].x = fmaf(a4.z, b4.x, acc[2].x);
        acc[2].y = fmaf(a4.z, b4.y, acc[2].y);
        acc[2].z = fmaf(a4.z, b4.z, acc[2].z);
        acc[2].w = fmaf(a4.z, b4.w, acc[2].w);
        acc[3].x = fmaf(a4.w, b4.x, acc[3].x);
        acc[3].y = fmaf(a4.w, b4.y, acc[3].y);
        acc[3].z = fmaf(a4.w, b4.z, acc[3].z);
        acc[3].w = fmaf(a4.w, b4.w, acc[3].w);
    }
    float4 bhv = make_float4(0.f, 0.f, 0.f, 0.f);
    if (which) bhv = *(const float4*)&bh[h * DEPTH + 4 * tj];
    #pragma unroll
    for (int r = 0; r < 4; ++r) {
        float4 o;
        o.x = SCALE2 * (acc[r].x + bhv.x);
        o.y = SCALE2 * (acc[r].y + bhv.y);
        o.z = SCALE2 * (acc[r].z + bhv.z);
        o.w = SCALE2 * (acc[r].w + bhv.w);
        *(float4*)&outp[(4 * ti + r) * DEPTH + 4 * tj] = o;
    }
}

// ============ additive-attention core ============
// score'[t,s] = sum_e (-2 va[e]) / (1 + exp2(qq2[t,e] + kkb2[s,e]))
//   (equals sum_e va[e]*tanh(q+k+b) minus a per-head constant -> softmax-invariant)
// then softmax over s, then out[t,d] = sum_s p[t,s]*Kh[s,d] / l[t]
__global__ __launch_bounds__(256) void attn_kernel(
    const float* __restrict__ qq2, const float* __restrict__ kkb2,
    const float* __restrict__ Kh, const float* __restrict__ va_h,
    float* __restrict__ merged)
{
    __shared__ float qq_s[16][68];
    __shared__ float kk_s[64][68];
    __shared__ float sc_s[16][512];
    __shared__ __align__(16) float va_s[64];
    __shared__ float inv_s[16];

    const int tid = threadIdx.x;
    const int t0 = blockIdx.x * 16;
    const int h = blockIdx.y;
    const int b = blockIdx.z;
    const int w = tid >> 6;   // wave 0..3
    const int l = tid & 63;   // lane

    const float* qq_p = qq2 + ((b * NH + h) * T_SEQ + t0) * DEPTH;
    const float* kk_p = kkb2 + ((size_t)(b * NH + h) * T_SEQ) * DEPTH;
    const float* K_p = Kh + ((size_t)(b * NH + h) * T_SEQ) * DEPTH;

    {
        const int tr = tid >> 4;
        const int e4 = (tid & 15) * 4;
        *(float4*)&qq_s[tr][e4] = *(const float4*)&qq_p[tr * DEPTH + e4];
        if (tid < 64) va_s[tid] = -2.0f * va_h[h * DEPTH + tid];
    }

    // ---- score phase: 8 s-tiles of 64 ----
    for (int st = 0; st < 8; ++st) {
        __syncthreads();
        {
            const int e4 = (tid & 15) * 4;
            const int sr = tid >> 4;
            #pragma unroll
            for (int r = 0; r < 4; ++r) {
                const int s = sr + 16 * r;
                *(float4*)&kk_s[s][e4] = *(const float4*)&kk_p[(st * 64 + s) * DEPTH + e4];
            }
        }
        __syncthreads();
        #pragma unroll
        for (int tt = 0; tt < 4; ++tt) {
            const int t = w * 4 + tt;
            float acc = 0.f;
            #pragma unroll
            for (int e = 0; e < 64; e += 4) {
                float4 q4 = *(const float4*)&qq_s[t][e];
                float4 k4 = *(const float4*)&kk_s[l][e];
                float4 v4 = *(const float4*)&va_s[e];
                float y0 = __builtin_amdgcn_exp2f(q4.x + k4.x);
                float y1 = __builtin_amdgcn_exp2f(q4.y + k4.y);
                float y2 = __builtin_amdgcn_exp2f(q4.z + k4.z);
                float y3 = __builtin_amdgcn_exp2f(q4.w + k4.w);
                acc = fmaf(v4.x, __builtin_amdgcn_rcpf(1.0f + y0), acc);
                acc = fmaf(v4.y, __builtin_amdgcn_rcpf(1.0f + y1), acc);
                acc = fmaf(v4.z, __builtin_amdgcn_rcpf(1.0f + y2), acc);
                acc = fmaf(v4.w, __builtin_amdgcn_rcpf(1.0f + y3), acc);
            }
            sc_s[t][st * 64 + l] = acc;
        }
    }
    __syncthreads();

    // ---- softmax over s (each wave owns its 4 t-rows) ----
    #pragma unroll
    for (int tt = 0; tt < 4; ++tt) {
        const int t = w * 4 + tt;
        float v[8];
        float mx = -3.0e38f;
        #pragma unroll
        for (int r = 0; r < 8; ++r) { v[r] = sc_s[t][l + 64 * r]; mx = fmaxf(mx, v[r]); }
        #pragma unroll
        for (int off = 32; off > 0; off >>= 1) mx = fmaxf(mx, __shfl_xor(mx, off, 64));
        float sum = 0.f;
        #pragma unroll
        for (int r = 0; r < 8; ++r) {
            v[r] = __builtin_amdgcn_exp2f((v[r] - mx) * LOG2E);
            sum += v[r];
        }
        #pragma unroll
        for (int off = 32; off > 0; off >>= 1) sum += __shfl_xor(sum, off, 64);
        #pragma unroll
        for (int r = 0; r < 8; ++r) sc_s[t][l + 64 * r] = v[r];
        if (l == 0) inv_s[t] = 1.0f / sum;
    }

    // ---- attn @ K (K tiles reuse kk_s) ----
    float4 oacc = make_float4(0.f, 0.f, 0.f, 0.f);
    for (int st = 0; st < 8; ++st) {
        __syncthreads();
        {
            const int e4 = (tid & 15) * 4;
            const int sr = tid >> 4;
            #pragma unroll
            for (int r = 0; r < 4; ++r) {
                const int s = sr + 16 * r;
                *(float4*)&kk_s[s][e4] = *(const float4*)&K_p[(st * 64 + s) * DEPTH + e4];
            }
        }
        __syncthreads();
        const int sbase = st * 64;
        #pragma unroll
        for (int s4 = 0; s4 < 64; s4 += 4) {
            float4 p0 = *(const float4*)&sc_s[w * 4 + 0][sbase + s4];
            float4 p1 = *(const float4*)&sc_s[w * 4 + 1][sbase + s4];
            float4 p2 = *(const float4*)&sc_s[w * 4 + 2][sbase + s4];
            float4 p3 = *(const float4*)&sc_s[w * 4 + 3][sbase + s4];
            float kv0 = kk_s[s4 + 0][l];
            float kv1 = kk_s[s4 + 1][l];
            float kv2 = kk_s[s4 + 2][l];
            float kv3 = kk_s[s4 + 3][l];
            oacc.x = fmaf(p0.x, kv0, oacc.x);
            oacc.x = fmaf(p0.y, kv1, oacc.x);
            oacc.x = fmaf(p0.z, kv2, oacc.x);
            oacc.x = fmaf(p0.w, kv3, oacc.x);
            oacc.y = fmaf(p1.x, kv0, oacc.y);
            oacc.y = fmaf(p1.y, kv1, oacc.y);
            oacc.y = fmaf(p1.z, kv2, oacc.y);
            oacc.y = fmaf(p1.w, kv3, oacc.y);
            oacc.z = fmaf(p2.x, kv0, oacc.z);
            oacc.z = fmaf(p2.y, kv1, oacc.z);
            oacc.z = fmaf(p2.z, kv2, oacc.z);
            oacc.z = fmaf(p2.w, kv3, oacc.z);
            oacc.w = fmaf(p3.x, kv0, oacc.w);
            oacc.w = fmaf(p3.y, kv1, oacc.w);
            oacc.w = fmaf(p3.z, kv2, oacc.w);
            oacc.w = fmaf(p3.w, kv3, oacc.w);
        }
    }
    const float i0 = inv_s[w * 4 + 0];
    const float i1 = inv_s[w * 4 + 1];
    const float i2 = inv_s[w * 4 + 2];
    const float i3 = inv_s[w * 4 + 3];
    float* mp = merged + (size_t)(b * T_SEQ + t0 + w * 4) * UNITS_ + h * DEPTH + l;
    mp[0 * UNITS_] = oacc.x * i0;
    mp[1 * UNITS_] = oacc.y * i1;
    mp[2 * UNITS_] = oacc.z * i2;
    mp[3 * UNITS_] = oacc.w * i3;
}

extern "C" void kernel_launch(void* const* d_in, const int* in_sizes, int n_in,
                              void* d_out, int out_size, void* d_ws, size_t ws_size,
                              hipStream_t stream) {
    (void)in_sizes; (void)n_in; (void)out_size; (void)ws_size;
    const float* query = (const float*)d_in[0];
    const float* key   = (const float*)d_in[1];
    // d_in[2] (value), d_in[7] (Wv), d_in[8] (bv): dead in the reference
    const float* Wq   = (const float*)d_in[3];
    const float* bq   = (const float*)d_in[4];
    const float* Wk   = (const float*)d_in[5];
    const float* bk   = (const float*)d_in[6];
    const float* Wq_h = (const float*)d_in[9];
    const float* Wk_h = (const float*)d_in[10];
    const float* va_h = (const float*)d_in[11];
    const float* b_h  = (const float*)d_in[12];
    const float* Wo   = (const float*)d_in[13];
    const float* bo   = (const float*)d_in[14];

    float* out = (float*)d_out;
    float* ws = (float*)d_ws;
    const int NTOK = 2 * T_SEQ;       // 1024 rows
    const int SZ = NTOK * UNITS_;     // 524288 floats per buffer
    float* Qb      = ws;
    float* Kb      = Qb + SZ;
    float* qq2b    = Kb + SZ;
    float* kkb2b   = qq2b + SZ;
    float* Khb     = kkb2b + SZ;
    float* mergedb = Khb + SZ;

    // Q = query@Wq+bq ; K = key@Wk+bk   (z batches the two)
    gemm_bias<<<dim3(8, 32, 2), 256, 0, stream>>>(query, key, Wq, Wk, bq, bk,
                                                  Qb, Kb, NTOK, UNITS_, 512);
    // per-head projections (+ b_h, scale 2*log2e) and head-split K copy
    head_xform<<<dim3(8, 8, 4), 256, 0, stream>>>(Qb, Kb, Wq_h, Wk_h, b_h,
                                                  qq2b, kkb2b, Khb);
    // additive scores -> softmax -> attn@K
    attn_kernel<<<dim3(32, 8, 2), 256, 0, stream>>>(qq2b, kkb2b, Khb, va_h, mergedb);
    // out = merged@Wo + bo
    gemm_bias<<<dim3(8, 32, 1), 256, 0, stream>>>(mergedb, mergedb, Wo, Wo, bo, bo,
                                                  out, out, NTOK, UNITS_, 512);
}

// Round 2
// 192.149 us; speedup vs baseline: 1.5970x; 1.5970x over previous
//
#include <hip/hip_runtime.h>
#include <hip/hip_bf16.h>

#define T_SEQ 512
#define NH 8
#define DEPTH 64
#define UNITS_ 512
#define SCALE2 2.8853900817779268f   // 2*log2(e)
#define LOG2E 1.4426950408889634f

typedef __attribute__((ext_vector_type(8))) short short8;
typedef __attribute__((ext_vector_type(4))) float floatx4;

// ================= GEMM with bias: C = A@W + bias =================
// All matrices stride 512 (M=1024 rows via grid). Tile 64x64, 4x4 per thread.
__global__ __launch_bounds__(256) void gemm64(
    const float* __restrict__ A0, const float* __restrict__ W0,
    const float* __restrict__ bias0, float* __restrict__ C0,
    const float* __restrict__ A1, const float* __restrict__ W1,
    const float* __restrict__ bias1, float* __restrict__ C1)
{
    const float* A = blockIdx.z ? A1 : A0;
    const float* W = blockIdx.z ? W1 : W0;
    const float* bias = blockIdx.z ? bias1 : bias0;
    float* C = blockIdx.z ? C1 : C0;

    __shared__ float As[32][68];   // [k][m] transposed
    __shared__ float Bs[32][68];   // [k][n]

    const int tid = threadIdx.x;
    const int m0 = blockIdx.y * 64;
    const int n0 = blockIdx.x * 64;

    const int arow = tid >> 2;          // m 0..63
    const int acol = (tid & 3) * 8;     // k base 0,8,16,24
    const int bk = tid >> 3;            // k 0..31
    const int bn = (tid & 7) * 8;       // n base

    const int ti = tid >> 4;            // m = 4*ti
    const int tj = tid & 15;            // n = 4*tj

    float4 acc[4];
    acc[0] = acc[1] = acc[2] = acc[3] = make_float4(0.f, 0.f, 0.f, 0.f);

    for (int k0 = 0; k0 < 512; k0 += 32) {
        float4 av0 = *(const float4*)&A[(m0 + arow) * 512 + k0 + acol];
        float4 av1 = *(const float4*)&A[(m0 + arow) * 512 + k0 + acol + 4];
        float4 bv0 = *(const float4*)&W[(k0 + bk) * 512 + n0 + bn];
        float4 bv1 = *(const float4*)&W[(k0 + bk) * 512 + n0 + bn + 4];
        __syncthreads();
        As[acol + 0][arow] = av0.x;
        As[acol + 1][arow] = av0.y;
        As[acol + 2][arow] = av0.z;
        As[acol + 3][arow] = av0.w;
        As[acol + 4][arow] = av1.x;
        As[acol + 5][arow] = av1.y;
        As[acol + 6][arow] = av1.z;
        As[acol + 7][arow] = av1.w;
        *(float4*)&Bs[bk][bn] = bv0;
        *(float4*)&Bs[bk][bn + 4] = bv1;
        __syncthreads();
        #pragma unroll
        for (int kk = 0; kk < 32; ++kk) {
            float4 a4 = *(const float4*)&As[kk][4 * ti];
            float4 b4 = *(const float4*)&Bs[kk][4 * tj];
            acc[0].x = fmaf(a4.x, b4.x, acc[0].x);
            acc[0].y = fmaf(a4.x, b4.y, acc[0].y);
            acc[0].z = fmaf(a4.x, b4.z, acc[0].z);
            acc[0].w = fmaf(a4.x, b4.w, acc[0].w);
            acc[1].x = fmaf(a4.y, b4.x, acc[1].x);
            acc[1].y = fmaf(a4.y, b4.y, acc[1].y);
            acc[1].z = fmaf(a4.y, b4.z, acc[1].z);
            acc[1].w = fmaf(a4.y, b4.w, acc[1].w);
            acc[2].x = fmaf(a4.z, b4.x, acc[2].x);
            acc[2].y = fmaf(a4.z, b4.y, acc[2].y);
            acc[2].z = fmaf(a4.z, b4.z, acc[2].z);
            acc[2].w = fmaf(a4.z, b4.w, acc[2].w);
            acc[3].x = fmaf(a4.w, b4.x, acc[3].x);
            acc[3].y = fmaf(a4.w, b4.y, acc[3].y);
            acc[3].z = fmaf(a4.w, b4.z, acc[3].z);
            acc[3].w = fmaf(a4.w, b4.w, acc[3].w);
        }
    }
    float4 bb = *(const float4*)&bias[n0 + 4 * tj];
    #pragma unroll
    for (int r = 0; r < 4; ++r) {
        float4 o;
        float4 a = acc[r];
        o.x = a.x + bb.x; o.y = a.y + bb.y; o.z = a.z + bb.z; o.w = a.w + bb.w;
        *(float4*)&C[(m0 + 4 * ti + r) * 512 + n0 + 4 * tj] = o;
    }
}

// ============ per-head transform ============
// which=0: eq[b,h,t,e]  = exp2(SCALE2 * sum_d Q[b,t,h*64+d]*Wq_h[h,d,e])
// which=1: ekT[b,h,e,s] = exp2(SCALE2 * (sum_d K*Wk_h + b_h[h,e]))  (transposed)
//          KhT[b,h,d,s] = bf16(K[b,s,h*64+d])                       (transposed)
__global__ __launch_bounds__(256) void head_xform(
    const float* __restrict__ Qb, const float* __restrict__ Kb,
    const float* __restrict__ Wq_h, const float* __restrict__ Wk_h,
    const float* __restrict__ bh,
    float* __restrict__ eq, float* __restrict__ ekT,
    __hip_bfloat16* __restrict__ KhT)
{
    __shared__ float As[64][68];   // In^T: [d][s_local]
    __shared__ float Ws[64][68];   // W [d][e]; reused as transpose buffer

    const int tid = threadIdx.x;
    const int t0 = blockIdx.x * 64;
    const int h = blockIdx.y;
    const int which = blockIdx.z & 1;
    const int b = blockIdx.z >> 1;
    const int bh_i = b * NH + h;

    const float* In = which ? Kb : Qb;
    const float* Wp = (which ? Wk_h : Wq_h) + h * 64 * 64;

    const int e4 = (tid & 15) * 4;
    const int tr = tid >> 4;

    #pragma unroll
    for (int r = 0; r < 4; ++r) {
        const int t = tr + 16 * r;
        float4 v = *(const float4*)&In[(b * 512 + t0 + t) * 512 + h * 64 + e4];
        As[e4 + 0][t] = v.x;
        As[e4 + 1][t] = v.y;
        As[e4 + 2][t] = v.z;
        As[e4 + 3][t] = v.w;
        *(float4*)&Ws[t][e4] = *(const float4*)&Wp[t * 64 + e4];   // t plays role of d
    }
    __syncthreads();

    const int ti = tid >> 4;
    const int tj = tid & 15;
    float4 acc[4];
    acc[0] = acc[1] = acc[2] = acc[3] = make_float4(0.f, 0.f, 0.f, 0.f);
    #pragma unroll 8
    for (int d = 0; d < 64; ++d) {
        float4 a4 = *(const float4*)&As[d][4 * ti];
        float4 b4 = *(const float4*)&Ws[d][4 * tj];
        acc[0].x = fmaf(a4.x, b4.x, acc[0].x);
        acc[0].y = fmaf(a4.x, b4.y, acc[0].y);
        acc[0].z = fmaf(a4.x, b4.z, acc[0].z);
        acc[0].w = fmaf(a4.x, b4.w, acc[0].w);
        acc[1].x = fmaf(a4.y, b4.x, acc[1].x);
        acc[1].y = fmaf(a4.y, b4.y, acc[1].y);
        acc[1].z = fmaf(a4.y, b4.z, acc[1].z);
        acc[1].w = fmaf(a4.y, b4.w, acc[1].w);
        acc[2].x = fmaf(a4.z, b4.x, acc[2].x);
        acc[2].y = fmaf(a4.z, b4.y, acc[2].y);
        acc[2].z = fmaf(a4.z, b4.z, acc[2].z);
        acc[2].w = fmaf(a4.z, b4.w, acc[2].w);
        acc[3].x = fmaf(a4.w, b4.x, acc[3].x);
        acc[3].y = fmaf(a4.w, b4.y, acc[3].y);
        acc[3].z = fmaf(a4.w, b4.z, acc[3].z);
        acc[3].w = fmaf(a4.w, b4.w, acc[3].w);
    }

    if (which == 0) {
        float* outp = eq + (bh_i * 512 + t0) * 64;
        #pragma unroll
        for (int r = 0; r < 4; ++r) {
            float4 o;
            o.x = __builtin_amdgcn_exp2f(SCALE2 * acc[r].x);
            o.y = __builtin_amdgcn_exp2f(SCALE2 * acc[r].y);
            o.z = __builtin_amdgcn_exp2f(SCALE2 * acc[r].z);
            o.w = __builtin_amdgcn_exp2f(SCALE2 * acc[r].w);
            *(float4*)&outp[(4 * ti + r) * 64 + 4 * tj] = o;
        }
        return;
    }

    // which == 1
    float4 bhv = *(const float4*)&bh[h * 64 + 4 * tj];
    __syncthreads();   // all waves done reading Ws
    #pragma unroll
    for (int r = 0; r < 4; ++r) {
        // e = 4*tj + c (row of transpose buffer), s_local = 4*ti + r
        Ws[4 * tj + 0][4 * ti + r] = __builtin_amdgcn_exp2f(SCALE2 * (acc[r].x + bhv.x));
        Ws[4 * tj + 1][4 * ti + r] = __builtin_amdgcn_exp2f(SCALE2 * (acc[r].y + bhv.y));
        Ws[4 * tj + 2][4 * ti + r] = __builtin_amdgcn_exp2f(SCALE2 * (acc[r].z + bhv.z));
        Ws[4 * tj + 3][4 * ti + r] = __builtin_amdgcn_exp2f(SCALE2 * (acc[r].w + bhv.w));
    }
    __syncthreads();

    // coalesced transposed writes: thread -> row dd, 16-col chunk
    const int dd = tid >> 2;
    const int sc = (tid & 3) * 16;
    float* ekp = ekT + ((size_t)bh_i * 64 + dd) * 512 + t0 + sc;
    #pragma unroll
    for (int c = 0; c < 4; ++c)
        *(float4*)&ekp[4 * c] = *(float4*)&Ws[dd][sc + 4 * c];

    // KhT bf16 from As (As[d][s_local] = K^T, untouched)
    __hip_bfloat16* kp = KhT + ((size_t)bh_i * 64 + dd) * 512 + t0 + sc;
    union { short8 v; short s[8]; } pk0, pk1;
    #pragma unroll
    for (int i = 0; i < 8; ++i) {
        __hip_bfloat16 b0 = __hip_bfloat16(As[dd][sc + i]);
        __hip_bfloat16 b1 = __hip_bfloat16(As[dd][sc + 8 + i]);
        pk0.s[i] = *(short*)&b0;
        pk1.s[i] = *(short*)&b1;
    }
    *(short8*)kp = pk0.v;
    *(short8*)(kp + 8) = pk1.v;
}

// ============ additive-attention core (register score + MFMA P@K) ============
// score'[t,s] = sum_e (-2 va[e]) * rcp(1 + eq[t][e]*ek[e][s])   (softmax-invariant)
// p = softmax (no max-subtract: |score'| <= 2*sum|va| ~ 5, exp safe in fp32)
// out[t,d] = sum_s p[t,s]*K[s,d] via bf16 MFMA 16x16x32
__global__ __launch_bounds__(512, 4) void attn_v2(
    const float* __restrict__ eq, const float* __restrict__ ekT,
    const __hip_bfloat16* __restrict__ KhT, const float* __restrict__ va_h,
    float* __restrict__ merged)
{
    __shared__ __hip_bfloat16 pA[16][520];   // p in MFMA-A layout source, bf16
    __shared__ float wsum[16][8];

    const int tid = threadIdx.x;
    const int w = tid >> 6;
    const int l = tid & 63;
    const int t0 = blockIdx.x * 16;
    const int h = blockIdx.y;
    const int b = blockIdx.z;
    const int bh_i = b * NH + h;

    const float* eq_p = eq + ((size_t)bh_i * 512 + t0) * 64;
    const float* ekT_p = ekT + (size_t)bh_i * 64 * 512 + tid;   // this thread's s
    const float* va_p = va_h + h * 64;

    float acc[16];
    #pragma unroll
    for (int t = 0; t < 16; ++t) acc[t] = 0.f;

    #pragma unroll
    for (int e0 = 0; e0 < 64; e0 += 16) {
        float ekv[16];
        #pragma unroll
        for (int j = 0; j < 16; ++j) ekv[j] = ekT_p[(e0 + j) * 512];
        float nv[16];
        #pragma unroll
        for (int j = 0; j < 16; ++j) nv[j] = -2.0f * va_p[e0 + j];
        #pragma unroll
        for (int t = 0; t < 16; ++t) {
            float a = acc[t];
            #pragma unroll
            for (int q = 0; q < 4; ++q) {
                float4 e4 = *(const float4*)&eq_p[t * 64 + e0 + q * 4];  // uniform -> s_load
                a = fmaf(nv[q * 4 + 0], __builtin_amdgcn_rcpf(fmaf(e4.x, ekv[q * 4 + 0], 1.0f)), a);
                a = fmaf(nv[q * 4 + 1], __builtin_amdgcn_rcpf(fmaf(e4.y, ekv[q * 4 + 1], 1.0f)), a);
                a = fmaf(nv[q * 4 + 2], __builtin_amdgcn_rcpf(fmaf(e4.z, ekv[q * 4 + 2], 1.0f)), a);
                a = fmaf(nv[q * 4 + 3], __builtin_amdgcn_rcpf(fmaf(e4.w, ekv[q * 4 + 3], 1.0f)), a);
            }
            acc[t] = a;
        }
    }

    // exp (no max-subtract; bounded) + per-t sum across 512 threads
    float ev[16];
    #pragma unroll
    for (int t = 0; t < 16; ++t) {
        float s = __builtin_amdgcn_exp2f(acc[t] * LOG2E);
        ev[t] = s;
        #pragma unroll
        for (int off = 32; off > 0; off >>= 1) s += __shfl_xor(s, off, 64);
        if (l == 0) wsum[t][w] = s;
    }
    __syncthreads();
    #pragma unroll
    for (int t = 0; t < 16; ++t) {
        float4 s0 = *(float4*)&wsum[t][0];
        float4 s1 = *(float4*)&wsum[t][4];
        float inv = 1.0f / (((s0.x + s0.y) + (s0.z + s0.w)) + ((s1.x + s1.y) + (s1.z + s1.w)));
        pA[t][tid] = __hip_bfloat16(ev[t] * inv);   // normalized p, bf16
    }
    __syncthreads();

    // P (16x512) @ K (512x64): 4 waves, wave w owns d-range [16w,16w+16)
    if (w < 4) {
        const __hip_bfloat16* kp = KhT + (size_t)bh_i * 64 * 512
                                   + ((size_t)(w * 16 + (l & 15))) * 512 + (l >> 4) * 8;
        const __hip_bfloat16* ap = &pA[l & 15][(l >> 4) * 8];
        floatx4 oacc = {0.f, 0.f, 0.f, 0.f};
        #pragma unroll
        for (int kt = 0; kt < 16; ++kt) {
            short8 af = *(const short8*)(ap + kt * 32);
            short8 bf = *(const short8*)(kp + kt * 32);
            oacc = __builtin_amdgcn_mfma_f32_16x16x32_bf16(af, bf, oacc, 0, 0, 0);
        }
        const int row = (l >> 4) * 4;        // t_local base
        const int col = w * 16 + (l & 15);   // d
        float* mp = merged + ((size_t)(b * 512 + t0 + row)) * 512 + h * 64 + col;
        #pragma unroll
        for (int r = 0; r < 4; ++r) mp[r * 512] = oacc[r];
    }
}

extern "C" void kernel_launch(void* const* d_in, const int* in_sizes, int n_in,
                              void* d_out, int out_size, void* d_ws, size_t ws_size,
                              hipStream_t stream) {
    (void)in_sizes; (void)n_in; (void)out_size; (void)ws_size;
    const float* query = (const float*)d_in[0];
    const float* key   = (const float*)d_in[1];
    // d_in[2] (value), d_in[7] (Wv), d_in[8] (bv): dead in the reference
    const float* Wq   = (const float*)d_in[3];
    const float* bq   = (const float*)d_in[4];
    const float* Wk   = (const float*)d_in[5];
    const float* bk   = (const float*)d_in[6];
    const float* Wq_h = (const float*)d_in[9];
    const float* Wk_h = (const float*)d_in[10];
    const float* va_h = (const float*)d_in[11];
    const float* b_h  = (const float*)d_in[12];
    const float* Wo   = (const float*)d_in[13];
    const float* bo   = (const float*)d_in[14];

    float* out = (float*)d_out;
    float* ws = (float*)d_ws;
    const int SZ = 1024 * 512;        // 524288 floats
    float* Qb      = ws;
    float* Kb      = Qb + SZ;
    float* eqb     = Kb + SZ;
    float* ekTb    = eqb + SZ;
    float* mergedb = ekTb + SZ;
    __hip_bfloat16* KhTb = (__hip_bfloat16*)(mergedb + SZ);   // 524288 bf16

    // Q = query@Wq+bq ; K = key@Wk+bk
    gemm64<<<dim3(8, 16, 2), 256, 0, stream>>>(query, Wq, bq, Qb,
                                               key, Wk, bk, Kb);
    // per-head: eq = exp2(2log2e*q), ekT = exp2(2log2e*(k+b)) transposed, KhT bf16
    head_xform<<<dim3(8, 8, 4), 256, 0, stream>>>(Qb, Kb, Wq_h, Wk_h, b_h,
                                                  eqb, ekTb, KhTb);
    // scores -> softmax -> P@K (MFMA)
    attn_v2<<<dim3(32, 8, 2), 512, 0, stream>>>(eqb, ekTb, KhTb, va_h, mergedb);
    // out = merged@Wo + bo
    gemm64<<<dim3(8, 16, 1), 256, 0, stream>>>(mergedb, Wo, bo, out,
                                               mergedb, Wo, bo, out);
}